// Round 1
// baseline (496.563 us; speedup 1.0000x reference)
//
#include <hip/hip_runtime.h>

// QORNN: quantized orthogonal RNN.
// Exact-integer strategy: x -> int8 (scale 128), Wi/Wr/Wo -> int4-in-int8
// (scale 8), h -> int8 (scale 128). z_int = dot_i8(x,Wi) + dot_i8(h,Wr),
// z = z_int / 1024 exactly. modrelu + requantize done in fp32, exactly
// matching the reference op order -> bitwise-identical recurrence.
//
// 1 batch row per WG (256 WGs x 256 thr = 1 WG/CU). Thread j holds Wr row j
// (64 dwords) + Wi row j (16 dwords) in VGPRs. h double-buffered in LDS
// (broadcast reads). x staged per 16-step chunk, prefetched 1 chunk ahead.

#define TSEQ 1024
#define IDIM 64
#define HDIM 256
#define ODIM 16
#define CHUNK 16
#define NCHUNK (TSEQ / CHUNK)

__device__ __forceinline__ int sdot4i8(int a, int b, int c) {
#if __has_builtin(__builtin_amdgcn_sdot4)
    return __builtin_amdgcn_sdot4(a, b, c, false);
#else
    int r = c;
    r += ((a << 24) >> 24) * ((b << 24) >> 24);
    r += ((a << 16) >> 24) * ((b << 16) >> 24);
    r += ((a << 8)  >> 24) * ((b << 8)  >> 24);
    r += (a >> 24) * (b >> 24);
    return r;
#endif
}

// q = clip(round_half_even(f*s), lo, hi) per lane, packed to 4 int8.
__device__ __forceinline__ int qpack4(float4 f, float s, float lo, float hi) {
    int a = (int)fminf(fmaxf(rintf(f.x * s), lo), hi);
    int b = (int)fminf(fmaxf(rintf(f.y * s), lo), hi);
    int c = (int)fminf(fmaxf(rintf(f.z * s), lo), hi);
    int d = (int)fminf(fmaxf(rintf(f.w * s), lo), hi);
    return (a & 255) | ((b & 255) << 8) | ((c & 255) << 16) | ((d & 255) << 24);
}

__global__ __launch_bounds__(256, 1)
void qornn_kernel(const float* __restrict__ x, const float* __restrict__ Wi,
                  const float* __restrict__ Wr, const float* __restrict__ Wo,
                  const float* __restrict__ bias, float* __restrict__ out) {
    __shared__ alignas(16) int wstage[8192];   // 32 KB staging (Wi, Wr halves, then Wo resident)
    __shared__ alignas(16) int xbuf[2][256];   // 2 x (16 steps x 64 int8) = 2 KB
    __shared__ alignas(16) int hbuf[2][64];    // 2 x 256 int8 = 512 B

    const int tid = threadIdx.x;
    const int brow = blockIdx.x;

    // ---- stage Wi [256 x 64] fp32 -> int8 (scale 8), read own row to regs ----
    {
        const float4* wi4 = (const float4*)Wi;
        #pragma unroll
        for (int it = 0; it < 16; ++it) {
            int flat = it * 256 + tid;           // dword idx 0..4095
            wstage[flat] = qpack4(wi4[flat], 8.0f, -8.0f, 7.0f);
        }
    }
    __syncthreads();
    int4 wiq[4];
    {
        const int4* p = (const int4*)wstage;
        #pragma unroll
        for (int i = 0; i < 4; ++i) wiq[i] = p[tid * 4 + i];
    }
    __syncthreads();

    // ---- stage Wr [256 x 256] in two 32 KB halves; thread j keeps row j ----
    int4 wq[16];
    {
        const float4* wr4 = (const float4*)Wr;
        // half A: rows 0..127
        #pragma unroll
        for (int it = 0; it < 32; ++it) {
            int flat = it * 256 + tid;           // dword idx 0..8191
            wstage[flat] = qpack4(wr4[flat], 8.0f, -8.0f, 7.0f);
        }
        __syncthreads();
        if (tid < 128) {
            const int4* p = (const int4*)wstage;
            #pragma unroll
            for (int i = 0; i < 16; ++i) wq[i] = p[tid * 16 + i];
        }
        __syncthreads();
        // half B: rows 128..255
        #pragma unroll
        for (int it = 0; it < 32; ++it) {
            int flat = it * 256 + tid;
            wstage[flat] = qpack4(wr4[8192 + flat], 8.0f, -8.0f, 7.0f);
        }
        __syncthreads();
        if (tid >= 128) {
            const int4* p = (const int4*)wstage;
            #pragma unroll
            for (int i = 0; i < 16; ++i) wq[i] = p[(tid - 128) * 16 + i];
        }
        __syncthreads();
    }

    // ---- stage Wo [16 x 256] -> int8, stays resident in wstage[0..1023] ----
    {
        const float4* wo4 = (const float4*)Wo;
        #pragma unroll
        for (int it = 0; it < 4; ++it) {
            int flat = it * 256 + tid;           // dword idx 0..1023
            wstage[flat] = qpack4(wo4[flat], 8.0f, -8.0f, 7.0f);
        }
    }

    const float bv = bias[tid];

    // ---- prologue: chunk 0 of x, h0 = 0 ----
    const float4* rowf4 = (const float4*)(x + (size_t)brow * (TSEQ * IDIM));
    {
        float4 xf = rowf4[tid];                  // chunk 0: 1024 floats coalesced
        xbuf[0][tid] = qpack4(xf, 128.0f, -128.0f, 127.0f);
        if (tid < 64) hbuf[0][tid] = 0;
    }
    __syncthreads();

    // ---- main recurrence: 64 chunks x 16 steps ----
    for (int c = 0; c < NCHUNK; ++c) {
        float4 nf;
        if (c < NCHUNK - 1) nf = rowf4[(c + 1) * 256 + tid];   // prefetch next chunk
        const int xb = c & 1;
        const int* xbase = xbuf[xb];

        #pragma unroll
        for (int s = 0; s < CHUNK; ++s) {
            const int pb = s & 1;
            // broadcast-read h (256 int8 = 64 dwords)
            int4 hh[16];
            {
                const int4* hP = (const int4*)hbuf[pb];
                #pragma unroll
                for (int i = 0; i < 16; ++i) hh[i] = hP[i];
            }
            // read x_t (64 int8 = 16 dwords)
            int4 xx[4];
            {
                const int4* xP = (const int4*)(xbase + s * 16);
                #pragma unroll
                for (int i = 0; i < 4; ++i) xx[i] = xP[i];
            }
            // z_int = h . Wr_row  +  x . Wi_row   (scale 1/1024)
            int a0 = 0, a1 = 0, a2 = 0, a3 = 0;
            #pragma unroll
            for (int i = 0; i < 16; ++i) {
                a0 = sdot4i8(hh[i].x, wq[i].x, a0);
                a1 = sdot4i8(hh[i].y, wq[i].y, a1);
                a2 = sdot4i8(hh[i].z, wq[i].z, a2);
                a3 = sdot4i8(hh[i].w, wq[i].w, a3);
            }
            #pragma unroll
            for (int i = 0; i < 4; ++i) {
                a0 = sdot4i8(xx[i].x, wiq[i].x, a0);
                a1 = sdot4i8(xx[i].y, wiq[i].y, a1);
                a2 = sdot4i8(xx[i].z, wiq[i].z, a2);
                a3 = sdot4i8(xx[i].w, wiq[i].w, a3);
            }
            const int z = (a0 + a1) + (a2 + a3);

            // modrelu + 8-bit requantize, exactly matching reference fp32 order:
            // zf = z/1024 (exact); m = relu(|zf| + b); f = sign(zf)*m*128 (exact);
            // h_new = clip(round_half_even(f), -128, 127)
            const float zf = (float)z * 0.0009765625f;
            const float t1 = fabsf(zf) + bv;
            const float t2 = fmaxf(t1, 0.0f);
            const float r  = rintf(t2 * 128.0f);
            const float rp = fminf(r, 127.0f);   // positive clip
            const float rn = fminf(r, 128.0f);   // negative side clips at -128
            int hnew = (z < 0) ? -(int)rn : (int)rp;
            hnew = (z == 0) ? 0 : hnew;          // sign(0) = 0

            ((signed char*)hbuf[pb ^ 1])[tid] = (signed char)hnew;

            if (s == CHUNK - 1 && c < NCHUNK - 1) {
                xbuf[xb ^ 1][tid] = qpack4(nf, 128.0f, -128.0f, 127.0f);
            }
            __syncthreads();
        }
    }

    // ---- epilogue: out[b, o] = h_last . Wo_row(o) / 1024  (h_last in hbuf[0]) ----
    if (tid < ODIM) {
        const int4* wo = (const int4*)wstage;    // row o = int4 idx [o*16 .. o*16+15]
        const int4* hl = (const int4*)hbuf[0];
        int a0 = 0, a1 = 0, a2 = 0, a3 = 0;
        #pragma unroll
        for (int i = 0; i < 16; ++i) {
            int4 w4 = wo[tid * 16 + i];
            int4 h4 = hl[i];
            a0 = sdot4i8(h4.x, w4.x, a0);
            a1 = sdot4i8(h4.y, w4.y, a1);
            a2 = sdot4i8(h4.z, w4.z, a2);
            a3 = sdot4i8(h4.w, w4.w, a3);
        }
        out[brow * ODIM + tid] = (float)((a0 + a1) + (a2 + a3)) * 0.0009765625f;
    }
}

extern "C" void kernel_launch(void* const* d_in, const int* in_sizes, int n_in,
                              void* d_out, int out_size, void* d_ws, size_t ws_size,
                              hipStream_t stream) {
    const float* x  = (const float*)d_in[0];   // [B, T, I]
    const float* Wi = (const float*)d_in[1];   // [H, I]
    const float* Wr = (const float*)d_in[2];   // [H, H]
    const float* Wo = (const float*)d_in[3];   // [O, H]
    const float* b  = (const float*)d_in[4];   // [H]
    float* out = (float*)d_out;                // [B, O]

    const int B = in_sizes[0] / (TSEQ * IDIM); // 256
    qornn_kernel<<<B, HDIM, 0, stream>>>(x, Wi, Wr, Wo, b, out);
}